// Round 2
// baseline (988.671 us; speedup 1.0000x reference)
//
#include <hip/hip_runtime.h>
#include <math.h>

// ============================================================================
// GeometricSuperpositionSearch — Cl(3,0) GA search, fp32.
// Basis order: [1, e1, e2, e3, e12, e13, e23, e123]
// Round 1: fix noise stream — JAX partitionable threefry 32-bit output is
//          o0 ^ o1 (XOR-fold of both words), counter=(hi=0, lo=idx).
// NOISE_MODE 0 = partitionable xor-fold (jax >= 0.5 default)
//            1 = legacy split-halves layout, 2 = o1 word, 3 = o0 word.
// ============================================================================

#define NOISE_MODE 0

#define DEV static __device__ __forceinline__

constexpr int Bz = 512;
constexpr int Cz = 256;
constexpr int MIDz = 128;
constexpr int Hz = 8;
constexpr int Nz = 4096;   // B*H
constexpr int Az = 5;
constexpr int NOISE_PER_D = Nz * Az;   // 20480

// ---------------- workspace layout (float offsets) ----------------
constexpr size_t OFF_ROTH  = 0;                    // 8 rotors  * 8
constexpr size_t OFF_ROTA  = OFF_ROTH + 64;        // 5 rotors  * 8
constexpr size_t OFF_ROTC  = OFF_ROTA + 40;        // 256 rotors* 8
constexpr size_t OFF_EXPL  = OFF_ROTC + 2048;      // 512
constexpr size_t OFF_DEN   = OFF_EXPL + 512;       // 4096
constexpr size_t OFF_BVE   = OFF_DEN + 4096;       // 4096
constexpr size_t OFF_HV    = OFF_BVE + 4096;       // 4096
constexpr size_t OFF_ACT   = OFF_HV + 4096;        // 4096 (int)
constexpr size_t OFF_FIRST = OFF_ACT + 4096;       // 4096 (int)
constexpr size_t OFF_D     = OFF_FIRST + 4096;     // N*MID*8  (pred h3)
constexpr size_t OFF_A     = OFF_D + (size_t)Nz * MIDz * 8;  // hf ping
constexpr size_t OFF_B     = OFF_A + (size_t)Nz * Cz * 8;    // hf pong
constexpr size_t OFF_C     = OFF_B + (size_t)Nz * Cz * 8;    // dyn h'

// ---------------- Cl(3,0) geometric product ----------------
DEV void gp8(const float* a, const float* b, float* c) {
  c[0] = a[0]*b[0]+a[1]*b[1]+a[2]*b[2]+a[3]*b[3]-a[4]*b[4]-a[5]*b[5]-a[6]*b[6]-a[7]*b[7];
  c[1] = a[0]*b[1]+a[1]*b[0]-a[2]*b[4]-a[3]*b[5]+a[4]*b[2]+a[5]*b[3]-a[6]*b[7]-a[7]*b[6];
  c[2] = a[0]*b[2]+a[2]*b[0]+a[1]*b[4]-a[4]*b[1]-a[3]*b[6]+a[6]*b[3]+a[5]*b[7]+a[7]*b[5];
  c[3] = a[0]*b[3]+a[3]*b[0]+a[1]*b[5]-a[5]*b[1]+a[2]*b[6]-a[6]*b[2]-a[4]*b[7]-a[7]*b[4];
  c[4] = a[0]*b[4]+a[4]*b[0]+a[1]*b[2]-a[2]*b[1]-a[5]*b[6]+a[6]*b[5]+a[3]*b[7]+a[7]*b[3];
  c[5] = a[0]*b[5]+a[5]*b[0]+a[1]*b[3]-a[3]*b[1]+a[4]*b[6]-a[6]*b[4]-a[2]*b[7]-a[7]*b[2];
  c[6] = a[0]*b[6]+a[6]*b[0]+a[2]*b[3]-a[3]*b[2]-a[4]*b[5]+a[5]*b[4]+a[1]*b[7]+a[7]*b[1];
  c[7] = a[0]*b[7]+a[7]*b[0]+a[1]*b[6]+a[6]*b[1]+a[3]*b[4]+a[4]*b[3]-a[2]*b[5]-a[5]*b[2];
}

DEV void sandwich8(const float* R, const float* x, float* y) {
  float t[8];
  gp8(R, x, t);
  float Rr[8] = {R[0], R[1], R[2], R[3], -R[4], -R[5], -R[6], -R[7]};
  gp8(t, Rr, y);
}

// R = exp(-0.5 * scatter_bv(bv)) : cos|B| + sinc|B| * B
DEV void rotor_from_bv(const float* bv, float* R) {
  float c4 = -0.5f * bv[0], c5 = -0.5f * bv[1], c6 = -0.5f * bv[2];
  float t = sqrtf(c4*c4 + c5*c5 + c6*c6);
  float sinc = (t < 1e-6f) ? (1.0f - t*t/6.0f) : (sinf(t)/t);
  R[0] = cosf(t); R[1] = 0.f; R[2] = 0.f; R[3] = 0.f;
  R[4] = sinc*c4; R[5] = sinc*c5; R[6] = sinc*c6; R[7] = 0.f;
}

// ---------------- threefry2x32, key = (0, 42) ----------------
DEV unsigned tf_rotl(unsigned v, int n) { return (v << n) | (v >> (32 - n)); }

DEV void threefry2x32(unsigned x0, unsigned x1, unsigned& o0, unsigned& o1) {
  const unsigned k0 = 0u, k1 = 42u;
  const unsigned k2 = k0 ^ k1 ^ 0x1BD11BDAu;
  x0 += k0; x1 += k1;
#define TF_R(r) { x0 += x1; x1 = tf_rotl(x1, r); x1 ^= x0; }
  TF_R(13) TF_R(15) TF_R(26) TF_R(6)
  x0 += k1; x1 += k2 + 1u;
  TF_R(17) TF_R(29) TF_R(16) TF_R(24)
  x0 += k2; x1 += k0 + 2u;
  TF_R(13) TF_R(15) TF_R(26) TF_R(6)
  x0 += k0; x1 += k1 + 3u;
  TF_R(17) TF_R(29) TF_R(16) TF_R(24)
  x0 += k1; x1 += k2 + 4u;
  TF_R(13) TF_R(15) TF_R(26) TF_R(6)
  x0 += k2; x1 += k0 + 5u;
#undef TF_R
  o0 = x0; o1 = x1;
}

// XLA f32 erfinv (Giles polynomial)
DEV float erfinv32(float x) {
  float w = -log1pf(-x * x);
  float p;
  if (w < 5.0f) {
    w = w - 2.5f;
    p = 2.81022636e-08f;
    p = fmaf(p, w, 3.43273939e-07f);
    p = fmaf(p, w, -3.5233877e-06f);
    p = fmaf(p, w, -4.39150654e-06f);
    p = fmaf(p, w, 0.00021858087f);
    p = fmaf(p, w, -0.00125372503f);
    p = fmaf(p, w, -0.00417768164f);
    p = fmaf(p, w, 0.246640727f);
    p = fmaf(p, w, 1.50140941f);
  } else {
    w = sqrtf(w) - 3.0f;
    p = -0.000200214257f;
    p = fmaf(p, w, 0.000100950558f);
    p = fmaf(p, w, 0.00134934322f);
    p = fmaf(p, w, -0.00367342844f);
    p = fmaf(p, w, 0.00573950773f);
    p = fmaf(p, w, -0.0076224613f);
    p = fmaf(p, w, 0.00943887047f);
    p = fmaf(p, w, 1.00167406f);
    p = fmaf(p, w, 2.83297682f);
  }
  return p * x;
}

// noise[d, r, a] = jax.random.normal(key(42), (3,4096,5), f32) * 0.3
DEV float noise_val(int d, int r, int a) {
  unsigned idx = (unsigned)(d * NOISE_PER_D + r * Az + a);
  unsigned o0, o1, bits;
#if NOISE_MODE == 0
  threefry2x32(0u, idx, o0, o1);      // counter = (hi=0, lo=idx)
  bits = o0 ^ o1;                     // partitionable 32-bit: xor-fold
#elif NOISE_MODE == 1
  const unsigned HALF = (unsigned)(3 * NOISE_PER_D) / 2u;  // 30720
  unsigned j = (idx < HALF) ? idx : idx - HALF;
  threefry2x32(j, j + HALF, o0, o1);
  bits = (idx < HALF) ? o0 : o1;
#elif NOISE_MODE == 2
  threefry2x32(0u, idx, o0, o1);
  bits = o1;
#else
  threefry2x32(0u, idx, o0, o1);
  bits = o0;
#endif
  const float MINV = __uint_as_float(0xBF7FFFFFu);   // nextafter(-1, 0)
  float f = __uint_as_float((bits >> 9) | 0x3F800000u) - 1.0f;
  float u = fmaxf(MINV, f * 2.0f + MINV);            // hi-lo == 2.0f exactly
  const float SQRT2 = __uint_as_float(0x3FB504F3u);
  return (SQRT2 * erfinv32(u)) * 0.3f;
}

DEV float gelu_tanh(float x) {
  float x3 = (x * x) * x;
  float t = tanhf(0.7978845608028654f * (x + 0.044715f * x3));
  return x * (0.5f * (1.0f + t));
}

// ============================================================================
// kernels
// ============================================================================

__global__ void k_setup(const float* __restrict__ hyp_bv, const float* __restrict__ act_bv,
                        const float* __restrict__ d_rotor_bv,
                        float* __restrict__ rotH, float* __restrict__ rotA,
                        float* __restrict__ rotC, float* __restrict__ hyp_val) {
  int t = blockIdx.x * blockDim.x + threadIdx.x;
  if (t < 8) rotor_from_bv(hyp_bv + t * 3, rotH + t * 8);
  else if (t < 13) rotor_from_bv(act_bv + (t - 8) * 3, rotA + (t - 8) * 8);
  else if (t < 13 + 256) rotor_from_bv(d_rotor_bv + (t - 13) * 3, rotC + (t - 13) * 8);
  if (t < Nz) hyp_val[t] = 0.f;
}

__global__ void k_explore(const float* __restrict__ state, const float* __restrict__ w1,
                          const float* __restrict__ b1, const float* __restrict__ w2,
                          const float* __restrict__ b2, float* __restrict__ explore) {
  int b = blockIdx.x, c = threadIdx.x;
  const float4* xp = (const float4*)(state + ((size_t)b * Cz + c) * 8);
  float4 lo = xp[0], hi = xp[1];
  float g0 = lo.x * lo.x;
  float g1 = lo.y * lo.y + lo.z * lo.z + lo.w * lo.w;
  float g2 = hi.x * hi.x + hi.y * hi.y + hi.z * hi.z;
  float g3 = hi.w * hi.w;
  __shared__ float4 sm[256];
  sm[c] = make_float4(sqrtf(g0 + 1e-12f), sqrtf(g1 + 1e-12f),
                      sqrtf(g2 + 1e-12f), sqrtf(g3 + 1e-12f));
  __syncthreads();
  for (int s = 128; s > 0; s >>= 1) {
    if (c < s) {
      sm[c].x += sm[c + s].x; sm[c].y += sm[c + s].y;
      sm[c].z += sm[c + s].z; sm[c].w += sm[c + s].w;
    }
    __syncthreads();
  }
  if (c == 0) {
    float pooled[4] = {sm[0].x / 256.f, sm[0].y / 256.f, sm[0].z / 256.f, sm[0].w / 256.f};
    float theta = b2[0];
    for (int j = 0; j < 32; j++) {
      float hj = b1[j];
      for (int g = 0; g < 4; g++) hj = fmaf(pooled[g], w1[g * 32 + j], hj);
      hj = fmaxf(hj, 0.f);
      theta = fmaf(hj, w2[j], theta);
    }
    explore[b] = fabsf(tanhf(theta));
  }
}

__global__ void k_hyp(const float* __restrict__ state, const float* __restrict__ rotH,
                      float* __restrict__ hf) {
  int r = blockIdx.x, c = threadIdx.x;
  int h = r & 7, b = r >> 3;
  float R[8];
#pragma unroll
  for (int i = 0; i < 8; i++) R[i] = rotH[h * 8 + i];
  const float4* xp = (const float4*)(state + ((size_t)b * Cz + c) * 8);
  float4 lo = xp[0], hi = xp[1];
  float x[8] = {lo.x, lo.y, lo.z, lo.w, hi.x, hi.y, hi.z, hi.w};
  float y[8];
  sandwich8(R, x, y);
  float4* yp = (float4*)(hf + ((size_t)r * Cz + c) * 8);
  yp[0] = make_float4(y[0], y[1], y[2], y[3]);
  yp[1] = make_float4(y[4], y[5], y[6], y[7]);
}

__global__ void k_prednorm(const float* __restrict__ cur, float* __restrict__ denom,
                           float* __restrict__ bv_e) {
  int r = blockIdx.x, c = threadIdx.x;
  const float4* xp = (const float4*)(cur + ((size_t)r * Cz + c) * 8);
  float4 lo = xp[0], hi = xp[1];
  float ss = lo.x*lo.x + lo.y*lo.y + lo.z*lo.z + lo.w*lo.w
           + hi.x*hi.x + hi.y*hi.y + hi.z*hi.z + hi.w*hi.w;
  float bv = hi.x*hi.x + hi.y*hi.y + hi.z*hi.z;  // slots 4,5,6
  __shared__ float smn[256];
  __shared__ float smb[256];
  smn[c] = sqrtf(ss + 1e-6f);
  smb[c] = bv;
  __syncthreads();
  for (int s = 128; s > 0; s >>= 1) {
    if (c < s) { smn[c] += smn[c + s]; smb[c] += smb[c + s]; }
    __syncthreads();
  }
  if (c == 0) {
    denom[r] = smn[0] / 256.f + 1e-6f;
    bv_e[r]  = smb[0] / 256.f;
  }
}

// predict: clayernorm (via denom) -> clinear(MID x C) -> ggelu, write h3 [N,MID,8]
__global__ void k_predlin(const float* __restrict__ cur, const float* __restrict__ denom,
                          const float* __restrict__ nw, const float* __restrict__ lw,
                          const float* __restrict__ lb, float* __restrict__ h3) {
  int r = blockIdx.x, o = threadIdx.x;   // blockDim = 128
  float invd = 1.0f / denom[r];
  float acc[8] = {0, 0, 0, 0, 0, 0, 0, 0};
  const float4* lwr = (const float4*)(lw + (size_t)o * Cz);
  const float* row = cur + (size_t)r * Cz * 8;
  for (int c4 = 0; c4 < Cz / 4; c4++) {
    float4 w4 = lwr[c4];
    int c = c4 * 4;
#pragma unroll
    for (int k = 0; k < 4; k++) {
      float wk = (k == 0) ? w4.x : (k == 1) ? w4.y : (k == 2) ? w4.z : w4.w;
      float sc = nw[c + k] * invd;
      const float* x = row + (size_t)(c + k) * 8;
#pragma unroll
      for (int dd = 0; dd < 8; dd++) acc[dd] = fmaf(wk, x[dd] * sc, acc[dd]);
    }
  }
  float hv[8];
  float nsq = 0.f;
#pragma unroll
  for (int dd = 0; dd < 8; dd++) { hv[dd] = acc[dd] + lb[o * 8 + dd]; nsq += hv[dd] * hv[dd]; }
  float nn = sqrtf(nsq + 1e-6f);
  float sc2 = gelu_tanh(nn) / (nn + 1e-6f);
  float* op = h3 + ((size_t)r * MIDz + o) * 8;
#pragma unroll
  for (int dd = 0; dd < 8; dd++) op[dd] = hv[dd] * sc2;
}

// heads: policy + noise -> argmax action
__global__ void k_heads(const float* __restrict__ h3, const float* __restrict__ pw,
                        const float* __restrict__ pb, const float* __restrict__ bv_e,
                        const float* __restrict__ explore, int d,
                        int* __restrict__ action, int* __restrict__ first_act) {
  int r = blockIdx.x * blockDim.x + threadIdx.x;
  if (r >= Nz) return;
  float pol[Az];
#pragma unroll
  for (int a = 0; a < Az; a++) pol[a] = pb[a];
  const float* hr = h3 + (size_t)r * MIDz * 8;
  for (int o = 0; o < MIDz; o++) {
    const float* hp = hr + (size_t)o * 8;
#pragma unroll
    for (int k = 0; k < 3; k++) {
      float v = hp[1 + k];
      const float* pwj = pw + (size_t)(o * 3 + k) * Az;
#pragma unroll
      for (int a = 0; a < Az; a++) pol[a] = fmaf(v, pwj[a], pol[a]);
    }
  }
  float coef = explore[r >> 3] * bv_e[r];
  int best = 0;
  float bs = -INFINITY;
  for (int a = 0; a < Az; a++) {
    float s = pol[a] + coef * noise_val(d, r, a);
    if (s > bs) { bs = s; best = a; }
  }
  action[r] = best;
  if (d == 0) first_act[r] = best;
}

// dynamics part A: action rotor sandwich -> ns; layernorm+ggelu+channel rotor -> h'
__global__ void k_dynA(const float* __restrict__ cur, const int* __restrict__ action,
                       const float* __restrict__ rotA, const float* __restrict__ rotC,
                       const float* __restrict__ dnw, float* __restrict__ ns,
                       float* __restrict__ hbuf) {
  int r = blockIdx.x, c = threadIdx.x;
  int a = action[r];
  float R[8];
#pragma unroll
  for (int i = 0; i < 8; i++) R[i] = rotA[a * 8 + i];
  const float4* xp = (const float4*)(cur + ((size_t)r * Cz + c) * 8);
  float4 lo = xp[0], hi = xp[1];
  float x[8] = {lo.x, lo.y, lo.z, lo.w, hi.x, hi.y, hi.z, hi.w};
  float y[8];
  sandwich8(R, x, y);
  float4* yp = (float4*)(ns + ((size_t)r * Cz + c) * 8);
  yp[0] = make_float4(y[0], y[1], y[2], y[3]);
  yp[1] = make_float4(y[4], y[5], y[6], y[7]);
  float ssq = 0.f;
#pragma unroll
  for (int i = 0; i < 8; i++) ssq += y[i] * y[i];
  __shared__ float sm[256];
  __shared__ float dsh;
  sm[c] = sqrtf(ssq + 1e-6f);
  __syncthreads();
  for (int s = 128; s > 0; s >>= 1) {
    if (c < s) sm[c] += sm[c + s];
    __syncthreads();
  }
  if (c == 0) dsh = sm[0] / 256.f + 1e-6f;
  __syncthreads();
  float invd = 1.0f / dsh;
  float h[8];
  float sc = dnw[c] * invd;
  float nsq = 0.f;
#pragma unroll
  for (int i = 0; i < 8; i++) { h[i] = y[i] * sc; nsq += h[i] * h[i]; }
  float nn = sqrtf(nsq + 1e-6f);
  float g = gelu_tanh(nn) / (nn + 1e-6f);
#pragma unroll
  for (int i = 0; i < 8; i++) h[i] *= g;
  float Rc[8];
#pragma unroll
  for (int i = 0; i < 8; i++) Rc[i] = rotC[c * 8 + i];
  float hp[8];
  sandwich8(Rc, h, hp);
  float4* op = (float4*)(hbuf + ((size_t)r * Cz + c) * 8);
  op[0] = make_float4(hp[0], hp[1], hp[2], hp[3]);
  op[1] = make_float4(hp[4], hp[5], hp[6], hp[7]);
}

// dynamics part B: clinear(C x C) + residual into ns; reward reduce -> hyp_val
__global__ void k_dynlin(const float* __restrict__ hbuf, const float* __restrict__ lw,
                         const float* __restrict__ lb, const float* __restrict__ rw,
                         const float* __restrict__ rb, float* __restrict__ ns,
                         float* __restrict__ hyp_val, float discf) {
  int r = blockIdx.x, o = threadIdx.x;   // blockDim = 256
  float acc[8] = {0, 0, 0, 0, 0, 0, 0, 0};
  const float4* lwr = (const float4*)(lw + (size_t)o * Cz);
  const float* row = hbuf + (size_t)r * Cz * 8;
  for (int c4 = 0; c4 < Cz / 4; c4++) {
    float4 w4 = lwr[c4];
    int c = c4 * 4;
#pragma unroll
    for (int k = 0; k < 4; k++) {
      float wk = (k == 0) ? w4.x : (k == 1) ? w4.y : (k == 2) ? w4.z : w4.w;
      const float* x = row + (size_t)(c + k) * 8;
#pragma unroll
      for (int dd = 0; dd < 8; dd++) acc[dd] = fmaf(wk, x[dd], acc[dd]);
    }
  }
  float* np_ = ns + ((size_t)r * Cz + o) * 8;
  float out0 = 0.f;
#pragma unroll
  for (int dd = 0; dd < 8; dd++) {
    float v = np_[dd] + (acc[dd] + lb[o * 8 + dd]);
    np_[dd] = v;
    if (dd == 0) out0 = v;
  }
  __shared__ float sm[256];
  sm[o] = out0 * rw[o];
  __syncthreads();
  for (int s = 128; s > 0; s >>= 1) {
    if (o < s) sm[o] += sm[o + s];
    __syncthreads();
  }
  if (o == 0) hyp_val[r] += discf * (sm[0] + rb[0]);
}

// terminal value head
__global__ void k_term(const float* __restrict__ h3, const float* __restrict__ vw,
                       const float* __restrict__ vb, float* __restrict__ hyp_val,
                       float discf) {
  int r = blockIdx.x * blockDim.x + threadIdx.x;
  if (r >= Nz) return;
  float v = vb[0];
  const float* hr = h3 + (size_t)r * MIDz * 8;
  for (int o = 0; o < MIDz; o++) v = fmaf(hr[(size_t)o * 8], vw[o], v);
  hyp_val[r] += discf * v;
}

// softmax over H, scatter first actions, normalize
__global__ void k_out(const float* __restrict__ hyp_val, const int* __restrict__ first_act,
                      float* __restrict__ out) {
  int b = blockIdx.x * blockDim.x + threadIdx.x;
  if (b >= Bz) return;
  float hv[Hz];
  float m = -INFINITY;
#pragma unroll
  for (int h = 0; h < Hz; h++) { hv[h] = hyp_val[b * Hz + h]; m = fmaxf(m, hv[h]); }
  float e[Hz];
  float se = 0.f;
#pragma unroll
  for (int h = 0; h < Hz; h++) { e[h] = expf(hv[h] - m); se += e[h]; }
  float ap[Az] = {0, 0, 0, 0, 0};
#pragma unroll
  for (int h = 0; h < Hz; h++) ap[first_act[b * Hz + h]] += e[h] / se;
  float tot = 0.f;
#pragma unroll
  for (int a = 0; a < Az; a++) tot += ap[a];
  float dn = fmaxf(tot, 1e-8f);
#pragma unroll
  for (int a = 0; a < Az; a++) out[b * Az + a] = ap[a] / dn;
}

// ============================================================================

extern "C" void kernel_launch(void* const* d_in, const int* in_sizes, int n_in,
                              void* d_out, int out_size, void* d_ws, size_t ws_size,
                              hipStream_t stream) {
  const float* state      = (const float*)d_in[0];
  const float* hyp_bv     = (const float*)d_in[1];
  const float* sp_w1      = (const float*)d_in[2];
  const float* sp_b1      = (const float*)d_in[3];
  const float* sp_w2      = (const float*)d_in[4];
  const float* sp_b2      = (const float*)d_in[5];
  const float* p_norm_w   = (const float*)d_in[6];
  const float* p_lin_w    = (const float*)d_in[7];
  const float* p_lin_b    = (const float*)d_in[8];
  const float* p_vw       = (const float*)d_in[9];
  const float* p_vb       = (const float*)d_in[10];
  const float* p_pw       = (const float*)d_in[11];
  const float* p_pb       = (const float*)d_in[12];
  const float* act_bv     = (const float*)d_in[13];
  const float* d_norm_w   = (const float*)d_in[14];
  const float* d_rotor_bv = (const float*)d_in[15];
  const float* d_lin_w    = (const float*)d_in[16];
  const float* d_lin_b    = (const float*)d_in[17];
  const float* d_rw       = (const float*)d_in[18];
  const float* d_rb       = (const float*)d_in[19];
  float* out = (float*)d_out;
  float* ws  = (float*)d_ws;

  float* rotH    = ws + OFF_ROTH;
  float* rotA    = ws + OFF_ROTA;
  float* rotC    = ws + OFF_ROTC;
  float* explore = ws + OFF_EXPL;
  float* denom   = ws + OFF_DEN;
  float* bv_e    = ws + OFF_BVE;
  float* hyp_val = ws + OFF_HV;
  int*   action  = (int*)(ws + OFF_ACT);
  int*   first   = (int*)(ws + OFF_FIRST);
  float* bufD    = ws + OFF_D;
  float* bufA    = ws + OFF_A;
  float* bufB    = ws + OFF_B;
  float* bufC    = ws + OFF_C;

  k_setup<<<16, 256, 0, stream>>>(hyp_bv, act_bv, d_rotor_bv, rotH, rotA, rotC, hyp_val);
  k_explore<<<Bz, 256, 0, stream>>>(state, sp_w1, sp_b1, sp_w2, sp_b2, explore);
  k_hyp<<<Nz, 256, 0, stream>>>(state, rotH, bufA);

  const float discp[4] = {1.0f, 0.99f, (float)(0.99 * 0.99), (float)(0.99 * 0.99 * 0.99)};
  float* cur = bufA;
  float* nxt = bufB;
  for (int d = 0; d < 3; d++) {
    k_prednorm<<<Nz, 256, 0, stream>>>(cur, denom, bv_e);
    k_predlin<<<Nz, 128, 0, stream>>>(cur, denom, p_norm_w, p_lin_w, p_lin_b, bufD);
    k_heads<<<16, 256, 0, stream>>>(bufD, p_pw, p_pb, bv_e, explore, d, action, first);
    k_dynA<<<Nz, 256, 0, stream>>>(cur, action, rotA, rotC, d_norm_w, nxt, bufC);
    k_dynlin<<<Nz, 256, 0, stream>>>(bufC, d_lin_w, d_lin_b, d_rw, d_rb, nxt, hyp_val, discp[d]);
    float* t = cur; cur = nxt; nxt = t;
  }
  // terminal value
  k_prednorm<<<Nz, 256, 0, stream>>>(cur, denom, bv_e);
  k_predlin<<<Nz, 128, 0, stream>>>(cur, denom, p_norm_w, p_lin_w, p_lin_b, bufD);
  k_term<<<16, 256, 0, stream>>>(bufD, p_vw, p_vb, hyp_val, discp[3]);
  k_out<<<2, 256, 0, stream>>>(hyp_val, first, out);
}

// Round 3
// 464.649 us; speedup vs baseline: 2.1278x; 2.1278x over previous
//
#include <hip/hip_runtime.h>
#include <math.h>

// ============================================================================
// GeometricSuperpositionSearch — Cl(3,0) GA search, fp32.
// Basis order: [1, e1, e2, e3, e12, e13, e23, e123]
// Round 3: fused wave-per-row kernels.
//   k_pred: stage->norm->GEMM(W' = W^T * nw folded)->ggelu->policy/value head
//   k_dyn : rotor sandwich (y in regs) -> norm -> ggelu -> rotor -> LDS h'
//           -> GEMM -> residual + reward
//   hyp rotor folded into d=0 staging; h3/hbuf/denom/bv_e buffers eliminated.
// ============================================================================

#define NOISE_MODE 0
#define DEV static __device__ __forceinline__

constexpr int Bz = 512;
constexpr int Cz = 256;
constexpr int MIDz = 128;
constexpr int Hz = 8;
constexpr int Nz = 4096;   // B*H
constexpr int Az = 5;
constexpr int NOISE_PER_D = Nz * Az;   // 20480

// ---------------- workspace layout (float offsets) ----------------
constexpr size_t OFF_ROTH  = 0;                          // 8*8
constexpr size_t OFF_ROTA  = OFF_ROTH + 64;              // 5*8
constexpr size_t OFF_ROTC  = OFF_ROTA + 40;              // 256*8
constexpr size_t OFF_EXPL  = OFF_ROTC + 2048;            // 512
constexpr size_t OFF_HV    = OFF_EXPL + 512;             // 4096
constexpr size_t OFF_ACT   = OFF_HV + 4096;              // 4096 (int)
constexpr size_t OFF_FIRST = OFF_ACT + 4096;             // 4096 (int)
constexpr size_t OFF_WTP   = OFF_FIRST + 4096;           // 256*128 (W'^T pred, nw folded)
constexpr size_t OFF_WTD   = OFF_WTP + (size_t)Cz * MIDz;// 256*256 (W^T dyn)
constexpr size_t OFF_A     = OFF_WTD + (size_t)Cz * Cz;  // N*C*8 ping
constexpr size_t OFF_B     = OFF_A + (size_t)Nz * Cz * 8;// N*C*8 pong

// ---------------- Cl(3,0) geometric product ----------------
DEV void gp8(const float* a, const float* b, float* c) {
  c[0] = a[0]*b[0]+a[1]*b[1]+a[2]*b[2]+a[3]*b[3]-a[4]*b[4]-a[5]*b[5]-a[6]*b[6]-a[7]*b[7];
  c[1] = a[0]*b[1]+a[1]*b[0]-a[2]*b[4]-a[3]*b[5]+a[4]*b[2]+a[5]*b[3]-a[6]*b[7]-a[7]*b[6];
  c[2] = a[0]*b[2]+a[2]*b[0]+a[1]*b[4]-a[4]*b[1]-a[3]*b[6]+a[6]*b[3]+a[5]*b[7]+a[7]*b[5];
  c[3] = a[0]*b[3]+a[3]*b[0]+a[1]*b[5]-a[5]*b[1]+a[2]*b[6]-a[6]*b[2]-a[4]*b[7]-a[7]*b[4];
  c[4] = a[0]*b[4]+a[4]*b[0]+a[1]*b[2]-a[2]*b[1]-a[5]*b[6]+a[6]*b[5]+a[3]*b[7]+a[7]*b[3];
  c[5] = a[0]*b[5]+a[5]*b[0]+a[1]*b[3]-a[3]*b[1]+a[4]*b[6]-a[6]*b[4]-a[2]*b[7]-a[7]*b[2];
  c[6] = a[0]*b[6]+a[6]*b[0]+a[2]*b[3]-a[3]*b[2]-a[4]*b[5]+a[5]*b[4]+a[1]*b[7]+a[7]*b[1];
  c[7] = a[0]*b[7]+a[7]*b[0]+a[1]*b[6]+a[6]*b[1]+a[3]*b[4]+a[4]*b[3]-a[2]*b[5]-a[5]*b[2];
}

DEV void sandwich8(const float* R, const float* x, float* y) {
  float t[8];
  gp8(R, x, t);
  float Rr[8] = {R[0], R[1], R[2], R[3], -R[4], -R[5], -R[6], -R[7]};
  gp8(t, Rr, y);
}

DEV void rotor_from_bv(const float* bv, float* R) {
  float c4 = -0.5f * bv[0], c5 = -0.5f * bv[1], c6 = -0.5f * bv[2];
  float t = sqrtf(c4*c4 + c5*c5 + c6*c6);
  float sinc = (t < 1e-6f) ? (1.0f - t*t/6.0f) : (sinf(t)/t);
  R[0] = cosf(t); R[1] = 0.f; R[2] = 0.f; R[3] = 0.f;
  R[4] = sinc*c4; R[5] = sinc*c5; R[6] = sinc*c6; R[7] = 0.f;
}

// ---------------- threefry2x32, key = (0, 42) ----------------
DEV unsigned tf_rotl(unsigned v, int n) { return (v << n) | (v >> (32 - n)); }

DEV void threefry2x32(unsigned x0, unsigned x1, unsigned& o0, unsigned& o1) {
  const unsigned k0 = 0u, k1 = 42u;
  const unsigned k2 = k0 ^ k1 ^ 0x1BD11BDAu;
  x0 += k0; x1 += k1;
#define TF_R(r) { x0 += x1; x1 = tf_rotl(x1, r); x1 ^= x0; }
  TF_R(13) TF_R(15) TF_R(26) TF_R(6)
  x0 += k1; x1 += k2 + 1u;
  TF_R(17) TF_R(29) TF_R(16) TF_R(24)
  x0 += k2; x1 += k0 + 2u;
  TF_R(13) TF_R(15) TF_R(26) TF_R(6)
  x0 += k0; x1 += k1 + 3u;
  TF_R(17) TF_R(29) TF_R(16) TF_R(24)
  x0 += k1; x1 += k2 + 4u;
  TF_R(13) TF_R(15) TF_R(26) TF_R(6)
  x0 += k2; x1 += k0 + 5u;
#undef TF_R
  o0 = x0; o1 = x1;
}

DEV float erfinv32(float x) {
  float w = -log1pf(-x * x);
  float p;
  if (w < 5.0f) {
    w = w - 2.5f;
    p = 2.81022636e-08f;
    p = fmaf(p, w, 3.43273939e-07f);
    p = fmaf(p, w, -3.5233877e-06f);
    p = fmaf(p, w, -4.39150654e-06f);
    p = fmaf(p, w, 0.00021858087f);
    p = fmaf(p, w, -0.00125372503f);
    p = fmaf(p, w, -0.00417768164f);
    p = fmaf(p, w, 0.246640727f);
    p = fmaf(p, w, 1.50140941f);
  } else {
    w = sqrtf(w) - 3.0f;
    p = -0.000200214257f;
    p = fmaf(p, w, 0.000100950558f);
    p = fmaf(p, w, 0.00134934322f);
    p = fmaf(p, w, -0.00367342844f);
    p = fmaf(p, w, 0.00573950773f);
    p = fmaf(p, w, -0.0076224613f);
    p = fmaf(p, w, 0.00943887047f);
    p = fmaf(p, w, 1.00167406f);
    p = fmaf(p, w, 2.83297682f);
  }
  return p * x;
}

DEV float noise_val(int d, int r, int a) {
  unsigned idx = (unsigned)(d * NOISE_PER_D + r * Az + a);
  unsigned o0, o1, bits;
#if NOISE_MODE == 0
  threefry2x32(0u, idx, o0, o1);
  bits = o0 ^ o1;
#elif NOISE_MODE == 1
  const unsigned HALF = (unsigned)(3 * NOISE_PER_D) / 2u;
  unsigned j = (idx < HALF) ? idx : idx - HALF;
  threefry2x32(j, j + HALF, o0, o1);
  bits = (idx < HALF) ? o0 : o1;
#elif NOISE_MODE == 2
  threefry2x32(0u, idx, o0, o1);
  bits = o1;
#else
  threefry2x32(0u, idx, o0, o1);
  bits = o0;
#endif
  const float MINV = __uint_as_float(0xBF7FFFFFu);
  float f = __uint_as_float((bits >> 9) | 0x3F800000u) - 1.0f;
  float u = fmaxf(MINV, f * 2.0f + MINV);
  const float SQRT2 = __uint_as_float(0x3FB504F3u);
  return (SQRT2 * erfinv32(u)) * 0.3f;
}

DEV float gelu_tanh(float x) {
  float x3 = (x * x) * x;
  float t = tanhf(0.7978845608028654f * (x + 0.044715f * x3));
  return x * (0.5f * (1.0f + t));
}

// ============================================================================
// kernels
// ============================================================================

// prep: rotors, hyp_val init, transposed/folded weights
__global__ void k_prep(const float* __restrict__ hyp_bv, const float* __restrict__ act_bv,
                       const float* __restrict__ rot_bv, const float* __restrict__ plw,
                       const float* __restrict__ pnw, const float* __restrict__ dlw,
                       float* __restrict__ rotH, float* __restrict__ rotA,
                       float* __restrict__ rotC, float* __restrict__ hyp_val,
                       float* __restrict__ WtP, float* __restrict__ WtD) {
  int t = blockIdx.x * 256 + threadIdx.x;   // grid 256 -> 65536 threads
  if (t < Cz * Cz)   { int c = t >> 8, o = t & 255; WtD[t] = dlw[o * Cz + c]; }
  if (t < Cz * MIDz) { int c = t >> 7, o = t & 127; WtP[t] = plw[o * Cz + c] * pnw[c]; }
  if (t < Nz) hyp_val[t] = 0.f;
  if (t < 8) rotor_from_bv(hyp_bv + t * 3, rotH + t * 8);
  else if (t < 13) rotor_from_bv(act_bv + (t - 8) * 3, rotA + (t - 8) * 8);
  else if (t >= 16 && t < 16 + Cz) rotor_from_bv(rot_bv + (t - 16) * 3, rotC + (t - 16) * 8);
}

__global__ void k_explore(const float* __restrict__ state, const float* __restrict__ w1,
                          const float* __restrict__ b1, const float* __restrict__ w2,
                          const float* __restrict__ b2, float* __restrict__ explore) {
  int b = blockIdx.x, c = threadIdx.x;
  const float4* xp = (const float4*)(state + ((size_t)b * Cz + c) * 8);
  float4 lo = xp[0], hi = xp[1];
  float g0 = lo.x * lo.x;
  float g1 = lo.y * lo.y + lo.z * lo.z + lo.w * lo.w;
  float g2 = hi.x * hi.x + hi.y * hi.y + hi.z * hi.z;
  float g3 = hi.w * hi.w;
  __shared__ float4 sm[256];
  sm[c] = make_float4(sqrtf(g0 + 1e-12f), sqrtf(g1 + 1e-12f),
                      sqrtf(g2 + 1e-12f), sqrtf(g3 + 1e-12f));
  __syncthreads();
  for (int s = 128; s > 0; s >>= 1) {
    if (c < s) {
      sm[c].x += sm[c + s].x; sm[c].y += sm[c + s].y;
      sm[c].z += sm[c + s].z; sm[c].w += sm[c + s].w;
    }
    __syncthreads();
  }
  if (c == 0) {
    float pooled[4] = {sm[0].x / 256.f, sm[0].y / 256.f, sm[0].z / 256.f, sm[0].w / 256.f};
    float theta = b2[0];
    for (int j = 0; j < 32; j++) {
      float hj = b1[j];
      for (int g = 0; g < 4; g++) hj = fmaf(pooled[g], w1[g * 32 + j], hj);
      hj = fmaxf(hj, 0.f);
      theta = fmaf(hj, w2[j], theta);
    }
    explore[b] = fabsf(tanhf(theta));
  }
}

// fused predict: stage (+hyp rotor) -> norms -> GEMM -> ggelu -> head
// mode 0: policy + noise argmax -> action (+first);  mode 1: terminal value
__global__ __launch_bounds__(256) void k_pred(
    const float* __restrict__ src, int apply_hyp, int dstep, int mode,
    const float* __restrict__ rotH, const float* __restrict__ WtP,
    const float* __restrict__ lb, const float* __restrict__ pw,
    const float* __restrict__ pb, const float* __restrict__ vw,
    const float* __restrict__ vb, const float* __restrict__ explore,
    float* __restrict__ hyp_val, int* __restrict__ action,
    int* __restrict__ first_act, float termdisc) {
  __shared__ float4 xs[4][2 * Cz];            // per-wave row: [d4][c]
  int w = threadIdx.x >> 6, l = threadIdx.x & 63;
  int r = blockIdx.x * 4 + w;
  int b = r >> 3, h = r & 7;
  const float* row = apply_hyp ? (src + (size_t)b * Cz * 8) : (src + (size_t)r * Cz * 8);
  float Rh[8];
  if (apply_hyp) {
#pragma unroll
    for (int i = 0; i < 8; i++) Rh[i] = rotH[h * 8 + i];
  }
  float nsum = 0.f, bsum = 0.f;
#pragma unroll
  for (int g = 0; g < 4; g++) {
    int c = l + 64 * g;
    const float4* xp = (const float4*)(row + (size_t)c * 8);
    float4 v0 = xp[0], v1 = xp[1];
    float x[8] = {v0.x, v0.y, v0.z, v0.w, v1.x, v1.y, v1.z, v1.w};
    if (apply_hyp) {
      float y[8];
      sandwich8(Rh, x, y);
#pragma unroll
      for (int i = 0; i < 8; i++) x[i] = y[i];
    }
    float ss = 0.f;
#pragma unroll
    for (int i = 0; i < 8; i++) ss += x[i] * x[i];
    nsum += sqrtf(ss + 1e-6f);
    bsum += x[4] * x[4] + x[5] * x[5] + x[6] * x[6];
    xs[w][c]      = make_float4(x[0], x[1], x[2], x[3]);
    xs[w][Cz + c] = make_float4(x[4], x[5], x[6], x[7]);
  }
#pragma unroll
  for (int m = 1; m < 64; m <<= 1) {
    nsum += __shfl_xor(nsum, m);
    bsum += __shfl_xor(bsum, m);
  }
  float invd = 1.0f / (nsum / 256.f + 1e-6f);
  float bv_e = bsum / 256.f;

  float acc[2][8] = {{0,0,0,0,0,0,0,0},{0,0,0,0,0,0,0,0}};
#pragma unroll 2
  for (int c = 0; c < Cz; c++) {
    float4 xa = xs[w][c], xb = xs[w][Cz + c];
    float xv[8] = {xa.x, xa.y, xa.z, xa.w, xb.x, xb.y, xb.z, xb.w};
    float w0 = WtP[(size_t)c * MIDz + l];
    float w1v = WtP[(size_t)c * MIDz + l + 64];
#pragma unroll
    for (int dd = 0; dd < 8; dd++) {
      acc[0][dd] = fmaf(w0, xv[dd], acc[0][dd]);
      acc[1][dd] = fmaf(w1v, xv[dd], acc[1][dd]);
    }
  }
  float hh[2][8];
#pragma unroll
  for (int j = 0; j < 2; j++) {
    int o = l + 64 * j;
    float nsq = 0.f;
#pragma unroll
    for (int dd = 0; dd < 8; dd++) {
      hh[j][dd] = acc[j][dd] * invd + lb[o * 8 + dd];
      nsq += hh[j][dd] * hh[j][dd];
    }
    float nn = sqrtf(nsq + 1e-6f);
    float sc = gelu_tanh(nn) / (nn + 1e-6f);
#pragma unroll
    for (int dd = 0; dd < 8; dd++) hh[j][dd] *= sc;
  }
  if (mode == 0) {
    float pol[Az] = {0, 0, 0, 0, 0};
#pragma unroll
    for (int j = 0; j < 2; j++) {
      int o = l + 64 * j;
#pragma unroll
      for (int k = 0; k < 3; k++) {
        float v = hh[j][1 + k];
        const float* pwj = pw + (size_t)(o * 3 + k) * Az;
#pragma unroll
        for (int a = 0; a < Az; a++) pol[a] = fmaf(v, pwj[a], pol[a]);
      }
    }
#pragma unroll
    for (int m = 1; m < 64; m <<= 1) {
#pragma unroll
      for (int a = 0; a < Az; a++) pol[a] += __shfl_xor(pol[a], m);
    }
    if (l == 0) {
      float coef = explore[b] * bv_e;
      int best = 0;
      float bs = -INFINITY;
      for (int a = 0; a < Az; a++) {
        float s = pol[a] + pb[a] + coef * noise_val(dstep, r, a);
        if (s > bs) { bs = s; best = a; }
      }
      action[r] = best;
      if (dstep == 0) first_act[r] = best;
    }
  } else {
    float v = 0.f;
#pragma unroll
    for (int j = 0; j < 2; j++) v = fmaf(hh[j][0], vw[l + 64 * j], v);
#pragma unroll
    for (int m = 1; m < 64; m <<= 1) v += __shfl_xor(v, m);
    if (l == 0) hyp_val[r] += termdisc * (v + vb[0]);
  }
}

// fused dynamics: stage (+hyp rotor if d=0) -> action sandwich (y in regs)
// -> norm -> ggelu -> channel rotor -> LDS h' -> GEMM -> residual + reward
__global__ __launch_bounds__(256) void k_dyn(
    const float* __restrict__ src, float* __restrict__ dst, int apply_hyp,
    const int* __restrict__ action, const float* __restrict__ rotH,
    const float* __restrict__ rotA, const float* __restrict__ rotC,
    const float* __restrict__ dnw, const float* __restrict__ WtD,
    const float* __restrict__ lb, const float* __restrict__ rw,
    const float* __restrict__ rb, float* __restrict__ hyp_val, float discf) {
  __shared__ float4 xs[4][2 * Cz];
  int w = threadIdx.x >> 6, l = threadIdx.x & 63;
  int r = blockIdx.x * 4 + w;
  int b = r >> 3, h = r & 7;
  const float* row = apply_hyp ? (src + (size_t)b * Cz * 8) : (src + (size_t)r * Cz * 8);
  int a = action[r];
  float Ra[8];
#pragma unroll
  for (int i = 0; i < 8; i++) Ra[i] = rotA[a * 8 + i];
  float Rh[8];
  if (apply_hyp) {
#pragma unroll
    for (int i = 0; i < 8; i++) Rh[i] = rotH[h * 8 + i];
  }
  float y[4][8];
  float nsum = 0.f;
#pragma unroll
  for (int g = 0; g < 4; g++) {
    int c = l + 64 * g;
    const float4* xp = (const float4*)(row + (size_t)c * 8);
    float4 v0 = xp[0], v1 = xp[1];
    float x[8] = {v0.x, v0.y, v0.z, v0.w, v1.x, v1.y, v1.z, v1.w};
    if (apply_hyp) {
      float t[8];
      sandwich8(Rh, x, t);
#pragma unroll
      for (int i = 0; i < 8; i++) x[i] = t[i];
    }
    sandwich8(Ra, x, y[g]);
    float ss = 0.f;
#pragma unroll
    for (int i = 0; i < 8; i++) ss += y[g][i] * y[g][i];
    nsum += sqrtf(ss + 1e-6f);
  }
#pragma unroll
  for (int m = 1; m < 64; m <<= 1) nsum += __shfl_xor(nsum, m);
  float invd = 1.0f / (nsum / 256.f + 1e-6f);
#pragma unroll
  for (int g = 0; g < 4; g++) {
    int c = l + 64 * g;
    float sc = dnw[c] * invd;
    float hch[8];
    float nsq = 0.f;
#pragma unroll
    for (int i = 0; i < 8; i++) { hch[i] = y[g][i] * sc; nsq += hch[i] * hch[i]; }
    float nn = sqrtf(nsq + 1e-6f);
    float ge = gelu_tanh(nn) / (nn + 1e-6f);
#pragma unroll
    for (int i = 0; i < 8; i++) hch[i] *= ge;
    float Rc[8];
    const float4* rp = (const float4*)(rotC + (size_t)c * 8);
    float4 r0 = rp[0], r1 = rp[1];
    Rc[0] = r0.x; Rc[1] = r0.y; Rc[2] = r0.z; Rc[3] = r0.w;
    Rc[4] = r1.x; Rc[5] = r1.y; Rc[6] = r1.z; Rc[7] = r1.w;
    float hp[8];
    sandwich8(Rc, hch, hp);
    xs[w][c]      = make_float4(hp[0], hp[1], hp[2], hp[3]);
    xs[w][Cz + c] = make_float4(hp[4], hp[5], hp[6], hp[7]);
  }
  float acc[4][8] = {{0,0,0,0,0,0,0,0},{0,0,0,0,0,0,0,0},
                     {0,0,0,0,0,0,0,0},{0,0,0,0,0,0,0,0}};
#pragma unroll 2
  for (int c = 0; c < Cz; c++) {
    float4 xa = xs[w][c], xb = xs[w][Cz + c];
    float xv[8] = {xa.x, xa.y, xa.z, xa.w, xb.x, xb.y, xb.z, xb.w};
#pragma unroll
    for (int g = 0; g < 4; g++) {
      float wv = WtD[(size_t)c * Cz + l + 64 * g];
#pragma unroll
      for (int dd = 0; dd < 8; dd++) acc[g][dd] = fmaf(wv, xv[dd], acc[g][dd]);
    }
  }
  float rsum = 0.f;
  float* drow = dst + (size_t)r * Cz * 8;
#pragma unroll
  for (int g = 0; g < 4; g++) {
    int o = l + 64 * g;
    float out[8];
#pragma unroll
    for (int dd = 0; dd < 8; dd++)
      out[dd] = y[g][dd] + (acc[g][dd] + lb[o * 8 + dd]);
    float4* op = (float4*)(drow + (size_t)o * 8);
    op[0] = make_float4(out[0], out[1], out[2], out[3]);
    op[1] = make_float4(out[4], out[5], out[6], out[7]);
    rsum = fmaf(out[0], rw[o], rsum);
  }
#pragma unroll
  for (int m = 1; m < 64; m <<= 1) rsum += __shfl_xor(rsum, m);
  if (l == 0) hyp_val[r] += discf * (rsum + rb[0]);
}

__global__ void k_out(const float* __restrict__ hyp_val, const int* __restrict__ first_act,
                      float* __restrict__ out) {
  int b = blockIdx.x * blockDim.x + threadIdx.x;
  if (b >= Bz) return;
  float hv[Hz];
  float m = -INFINITY;
#pragma unroll
  for (int h = 0; h < Hz; h++) { hv[h] = hyp_val[b * Hz + h]; m = fmaxf(m, hv[h]); }
  float e[Hz];
  float se = 0.f;
#pragma unroll
  for (int h = 0; h < Hz; h++) { e[h] = expf(hv[h] - m); se += e[h]; }
  float ap[Az] = {0, 0, 0, 0, 0};
#pragma unroll
  for (int h = 0; h < Hz; h++) ap[first_act[b * Hz + h]] += e[h] / se;
  float tot = 0.f;
#pragma unroll
  for (int a = 0; a < Az; a++) tot += ap[a];
  float dn = fmaxf(tot, 1e-8f);
#pragma unroll
  for (int a = 0; a < Az; a++) out[b * Az + a] = ap[a] / dn;
}

// ============================================================================

extern "C" void kernel_launch(void* const* d_in, const int* in_sizes, int n_in,
                              void* d_out, int out_size, void* d_ws, size_t ws_size,
                              hipStream_t stream) {
  const float* state      = (const float*)d_in[0];
  const float* hyp_bv     = (const float*)d_in[1];
  const float* sp_w1      = (const float*)d_in[2];
  const float* sp_b1      = (const float*)d_in[3];
  const float* sp_w2      = (const float*)d_in[4];
  const float* sp_b2      = (const float*)d_in[5];
  const float* p_norm_w   = (const float*)d_in[6];
  const float* p_lin_w    = (const float*)d_in[7];
  const float* p_lin_b    = (const float*)d_in[8];
  const float* p_vw       = (const float*)d_in[9];
  const float* p_vb       = (const float*)d_in[10];
  const float* p_pw       = (const float*)d_in[11];
  const float* p_pb       = (const float*)d_in[12];
  const float* act_bv     = (const float*)d_in[13];
  const float* d_norm_w   = (const float*)d_in[14];
  const float* d_rotor_bv = (const float*)d_in[15];
  const float* d_lin_w    = (const float*)d_in[16];
  const float* d_lin_b    = (const float*)d_in[17];
  const float* d_rw       = (const float*)d_in[18];
  const float* d_rb       = (const float*)d_in[19];
  float* out = (float*)d_out;
  float* ws  = (float*)d_ws;

  float* rotH    = ws + OFF_ROTH;
  float* rotA    = ws + OFF_ROTA;
  float* rotC    = ws + OFF_ROTC;
  float* explore = ws + OFF_EXPL;
  float* hyp_val = ws + OFF_HV;
  int*   action  = (int*)(ws + OFF_ACT);
  int*   first   = (int*)(ws + OFF_FIRST);
  float* WtP     = ws + OFF_WTP;
  float* WtD     = ws + OFF_WTD;
  float* bufA    = ws + OFF_A;
  float* bufB    = ws + OFF_B;

  k_prep<<<256, 256, 0, stream>>>(hyp_bv, act_bv, d_rotor_bv, p_lin_w, p_norm_w,
                                  d_lin_w, rotH, rotA, rotC, hyp_val, WtP, WtD);
  k_explore<<<Bz, 256, 0, stream>>>(state, sp_w1, sp_b1, sp_w2, sp_b2, explore);

  const float discp[4] = {1.0f, 0.99f, (float)(0.99 * 0.99), (float)(0.99 * 0.99 * 0.99)};
  const float* cur = state;
  float* nxt = bufA;
  for (int d = 0; d < 3; d++) {
    int ah = (d == 0) ? 1 : 0;
    k_pred<<<Nz / 4, 256, 0, stream>>>(cur, ah, d, 0, rotH, WtP, p_lin_b, p_pw, p_pb,
                                       p_vw, p_vb, explore, hyp_val, action, first, 0.f);
    k_dyn<<<Nz / 4, 256, 0, stream>>>(cur, nxt, ah, action, rotH, rotA, rotC, d_norm_w,
                                      WtD, d_lin_b, d_rw, d_rb, hyp_val, discp[d]);
    cur = nxt;
    nxt = (d == 0) ? bufB : ((d == 1) ? bufA : bufB);
  }
  k_pred<<<Nz / 4, 256, 0, stream>>>(cur, 0, 0, 1, rotH, WtP, p_lin_b, p_pw, p_pb,
                                     p_vw, p_vb, explore, hyp_val, action, first,
                                     discp[3]);
  k_out<<<2, 256, 0, stream>>>(hyp_val, first, out);
}